// Round 5
// baseline (349.513 us; speedup 1.0000x reference)
//
#include <hip/hip_runtime.h>
#include <hip/hip_fp16.h>

// Fern patch-descriptor pipeline.
//   x:(64,8,128,128) f32, thresholds:(8,12) f32, table:(8,4096,32) f32,
//   chan_idx:(8,12,2) i32, offsets:(8,12,2,2) i32
//   out:(64, 32*114*114) f32
//
// R7: occupancy + MLP rework of fern_gather.
//   - 32x32 position tiles (40x40 halo, 51.2KB LDS), 1024 thr = 16 waves;
//     2 blocks/CU = 32 waves (max). Grid 64*16 = 1024 = exactly 4 blocks/CU
//     (zero tail). Seam tiles (start 88) recompute a few rows; the duplicate
//     vote writes carry identical bytes (benign).
//   - gather: all 8 table-row loads issued back-to-back into registers
//     (8 x dwordx4 in flight), then accumulated. launch_bounds(1024,8)
//     caps VGPR at 64 to hold 2-block residency.
//   - x-tile row stride 40 (not 32): fern_bits LDS reads conflict-free.
// table f32->f16 pre-pass and fern_pool unchanged from R6.

#define NN 64
#define CC 8
#define HH 128
#define WW 128
#define MM 8
#define KK 12
#define DD 32
#define OUTS 114
#define TT 19          // output tile edge (114 = 6*19 exact)
#define PT 25          // position tile edge = TT + POOL - 1
#define XT 33          // fused-kernel x tile edge = PT + L - 1
#define XSTRIDE (XT*XT)   // 1089
#define VSTRIDE 36        // vote row stride in halves (72 B rows, 8B-aligned)
#define NPOSI (PT*PT)     // 625
#define THREADS 640
#define POOLW 7

// K1 geometry: 120x120 unique grid, 4x4 tiles of 32x32 (starts 0,32,64,88)
#define PTK 32
#define XTK 40            // PTK + L - 1
#define XS2 (XTK*XTK)     // 1600
#define NPOS_IMG (120*120)
#define K1T 1024

#define VOTE_BYTES ((size_t)NN * NPOS_IMG * DD * 2)   // 58,982,400 B
#define TAB_ELEMS  (MM*4096*DD)                       // 1,048,576
#define TAB16_BYTES ((size_t)TAB_ELEMS * 2)           // 2,097,152 B

#define LDS_BYTES (CC*XSTRIDE*4 + NPOSI*VSTRIDE*2)   // fused fallback: 79848

// 8-byte LDS accessors: 4 halves <-> float4
__device__ __forceinline__ float4 ld4h(const __half* p) {
    union { float2 f; __half2 h[2]; } u;
    u.f = *(const float2*)p;
    float2 a = __half22float2(u.h[0]);
    float2 b = __half22float2(u.h[1]);
    return make_float4(a.x, a.y, b.x, b.y);
}
__device__ __forceinline__ void st4h(__half* p, float4 v) {
    union { float2 f; __half2 h[2]; } u;
    u.h[0] = __floats2half2_rn(v.x, v.y);
    u.h[1] = __floats2half2_rn(v.z, v.w);
    *(float2*)p = u.f;
}

// Shared bit/conf math: identical arithmetic order everywhere.
template<int XS, int XROW>
__device__ __forceinline__ void fern_bits(const float* __restrict__ xs, int pb,
                                          const float* __restrict__ thresholds,
                                          const int*   __restrict__ chan_idx,
                                          const int*   __restrict__ offsets,
                                          unsigned wreg[MM], float creg[MM])
{
    #pragma unroll
    for (int m = 0; m < MM; ++m) {
        unsigned word = 0u;
        float P = 1.f;                    // prod(1 + exp(-10|z|))
        #pragma unroll
        for (int k = 0; k < KK; ++k) {
            const int mk = m*KK + k;
            // compile-time mk -> wave-uniform scalar loads
            int c1  = chan_idx[mk*2 + 0];
            int c2  = chan_idx[mk*2 + 1];
            int dy1 = offsets[mk*4 + 0];
            int dx1 = offsets[mk*4 + 1];
            int dy2 = offsets[mk*4 + 2];
            int dx2 = offsets[mk*4 + 3];
            float thr = thresholds[mk];
            float p1 = xs[c1*XS + dy1*XROW + dx1 + pb];
            float p2 = xs[c2*XS + dy2*XROW + dx2 + pb];
            float z  = (p1 - p2) - thr;
            if (z > 0.f) word |= (1u << k);
            float e = __expf(-10.f * fabsf(z));
            P += P * e;                   // P *= (1+e), single v_fma
        }
        wreg[m] = word;
        creg[m] = __builtin_amdgcn_rcpf(P);   // conf = 1/P
    }
}

// ===================== table f32 -> f16 conversion =========================
__global__ __launch_bounds__(256)
void table_to_f16(const float* __restrict__ t, __half* __restrict__ t16)
{
    const int i = (blockIdx.x * 256 + threadIdx.x) * 8;
    float4 a = *(const float4*)(t + i);
    float4 b = *(const float4*)(t + i + 4);
    union { float4 f; __half2 h[4]; } o;
    o.h[0] = __floats2half2_rn(a.x, a.y);
    o.h[1] = __floats2half2_rn(a.z, a.w);
    o.h[2] = __floats2half2_rn(b.x, b.y);
    o.h[3] = __floats2half2_rn(b.z, b.w);
    *(float4*)(t16 + i) = o.f;
}

// ============ K1: bits + conf + f16 table gather (unique positions) ========
__global__ __launch_bounds__(K1T, 8)
void fern_gather(const float* __restrict__ x,
                 const float* __restrict__ thresholds,
                 const __half* __restrict__ table16,
                 const int*   __restrict__ chan_idx,
                 const int*   __restrict__ offsets,
                 __half* __restrict__ votes)
{
    __shared__ float4 xs4[CC*XS2/4];     // 51200 B
    float* xs = (float*)xs4;

    const int tile = blockIdx.x;             // 64 images x 16 tiles
    const int n    = tile >> 4;
    const int t2   = tile & 15;
    const int ti   = t2 >> 2;
    const int tj   = t2 & 3;
    const int pi0  = ti < 3 ? ti*PTK : 88;   // starts 0,32,64,88
    const int pj0  = tj < 3 ? tj*PTK : 88;

    const int tid = threadIdx.x;

    // stage 8x40x40 f32 tile as float4 (all starts %4==0 -> aligned)
    const float* xn = x + (size_t)n * (CC*HH*WW);
    for (int idx = tid; idx < CC*XS2/4; idx += K1T) {
        int c   = idx / 400;                 // 400 float4 / channel
        int rem = idx - c*400;
        int r   = rem / 10;                  // 10 float4 / row
        int c4  = rem - r*10;
        xs4[idx] = *(const float4*)(xn + (c*HH + pi0 + r)*WW + pj0 + c4*4);
    }
    __syncthreads();

    const int ty = tid >> 5;                 // 0..31
    const int tx = tid & 31;

    unsigned wreg[MM];
    float    creg[MM];
    fern_bits<XS2, XTK>(xs, ty*XTK + tx, thresholds, chan_idx, offsets,
                        wreg, creg);
    __syncthreads();   // all xs reads complete -> xs region reusable

    // Overlay on dead xs: c0buf f4[1024] @0 (16KB), c1buf f4[1024] @16KB,
    // wbuf u4[1024] @32KB. Total 48KB <= 51.2KB.
    float4* c0buf = (float4*)xs;
    float4* c1buf = (float4*)(xs + 4096);
    uint4*  wbuf  = (uint4*)(xs + 8192);

    {
        uint4 wv;
        wv.x = wreg[0] | (wreg[1] << 16);
        wv.y = wreg[2] | (wreg[3] << 16);
        wv.z = wreg[4] | (wreg[5] << 16);
        wv.w = wreg[6] | (wreg[7] << 16);
        wbuf[tid]  = wv;
        c0buf[tid] = make_float4(creg[0], creg[1], creg[2], creg[3]);
        c1buf[tid] = make_float4(creg[4], creg[5], creg[6], creg[7]);
    }
    __syncthreads();

    // Quad-cooperative gather: item = (pos,q); 4 lanes share pos, each lane
    // reads 16B (8 halves) of the 64B f16 table row. All 8 fern rows are
    // loaded back-to-back into registers (8 dwordx4 in flight), THEN
    // accumulated -- max memory-level parallelism per wave.
    #pragma unroll
    for (int it = 0; it < 4; ++it) {
        const int item = tid + it*K1T;
        const int pos  = item >> 2;
        const int q    = item & 3;
        uint4  wv = wbuf[pos];               // broadcast within quad
        float4 c0 = c0buf[pos];
        float4 c1 = c1buf[pos];
        const __half* tb = table16 + q*8;
        union U { float4 f; __half2 h[4]; };
        U t0, t1, t2, t3, t4, t5, t6, t7;
        t0.f = *(const float4*)(tb + ((0u<<12) + (wv.x & 0xFFFFu))*DD);
        t1.f = *(const float4*)(tb + ((1u<<12) + (wv.x >> 16    ))*DD);
        t2.f = *(const float4*)(tb + ((2u<<12) + (wv.y & 0xFFFFu))*DD);
        t3.f = *(const float4*)(tb + ((3u<<12) + (wv.y >> 16    ))*DD);
        t4.f = *(const float4*)(tb + ((4u<<12) + (wv.z & 0xFFFFu))*DD);
        t5.f = *(const float4*)(tb + ((5u<<12) + (wv.z >> 16    ))*DD);
        t6.f = *(const float4*)(tb + ((6u<<12) + (wv.w & 0xFFFFu))*DD);
        t7.f = *(const float4*)(tb + ((7u<<12) + (wv.w >> 16    ))*DD);
        float acc[8];
        #pragma unroll
        for (int j = 0; j < 8; ++j) acc[j] = 0.f;
#define ACC(T, cexpr) {                                                    \
        float cf = (cexpr);                                                \
        float2 v0 = __half22float2(T.h[0]);                                \
        float2 v1 = __half22float2(T.h[1]);                                \
        float2 v2 = __half22float2(T.h[2]);                                \
        float2 v3 = __half22float2(T.h[3]);                                \
        acc[0] += cf*v0.x; acc[1] += cf*v0.y;                              \
        acc[2] += cf*v1.x; acc[3] += cf*v1.y;                              \
        acc[4] += cf*v2.x; acc[5] += cf*v2.y;                              \
        acc[6] += cf*v3.x; acc[7] += cf*v3.y; }
        ACC(t0, c0.x)
        ACC(t1, c0.y)
        ACC(t2, c0.z)
        ACC(t3, c0.w)
        ACC(t4, c1.x)
        ACC(t5, c1.y)
        ACC(t6, c1.z)
        ACC(t7, c1.w)
#undef ACC
        // votes[gp][q*8 .. +7] as f16: 16B/lane, quad covers the 64B row,
        // consecutive pos -> contiguous per wave. Seam double-writes carry
        // identical bytes (same inputs) -> benign.
        const int py = pos >> 5;
        const int px = pos & 31;
        const int gp = n*NPOS_IMG + (pi0 + py)*120 + (pj0 + px);
        union { float4 f; __half2 h[4]; } o;
        o.h[0] = __floats2half2_rn(acc[0], acc[1]);
        o.h[1] = __floats2half2_rn(acc[2], acc[3]);
        o.h[2] = __floats2half2_rn(acc[4], acc[5]);
        o.h[3] = __floats2half2_rn(acc[6], acc[7]);
        *(float4*)(votes + (size_t)gp*DD + q*8) = o.f;
    }
}

// ====================== K2: pooling only ===================================
__global__ __launch_bounds__(THREADS, 8)
void fern_pool(const __half* __restrict__ votes,
               float* __restrict__ out)
{
    __shared__ float2 vsraw[NPOSI*VSTRIDE/4];   // 45000 B
    __half* vs = (__half*)vsraw;

    const int tile = blockIdx.x;         // 0..2303
    const int n    = tile / 36;
    const int t2   = tile - n*36;
    const int ti   = t2 / 6;
    const int tj   = t2 - ti*6;
    const int i0   = ti * TT;            // 0..95
    const int j0   = tj * TT;

    const int tid = threadIdx.x;

    // ---- stage 25x25x32 f16 votes tile; item = (pos, oct): 8B per lane ----
    const int pbase = n*NPOS_IMG + i0*120 + j0;
    for (int idx = tid; idx < NPOSI*8; idx += THREADS) {
        const int pos = idx >> 3;
        const int oct = idx & 7;
        const int y   = pos / PT;
        const int j   = pos - y*PT;
        const __half* src = votes + (size_t)(pbase + y*120 + j)*DD + oct*4;
        *(float2*)(vs + pos*VSTRIDE + oct*4) = *(const float2*)src;
    }
    __syncthreads();

    // ---- 3a: horizontal 7-window running sums (in-place) ----
    for (int w = tid; w < PT*8; w += THREADS) {
        int y  = w / 8;
        int d4 = w - y*8;
        float4 s = make_float4(0.f, 0.f, 0.f, 0.f);
        float4 ring[POOLW];
        #pragma unroll
        for (int j = 0; j < PT; ++j) {
            float4 v = ld4h(vs + (y*PT + j)*VSTRIDE + d4*4);
            if (j >= POOLW) {
                float4 o = ring[j % POOLW];
                s.x -= o.x; s.y -= o.y; s.z -= o.z; s.w -= o.w;
            }
            ring[j % POOLW] = v;
            s.x += v.x; s.y += v.y; s.z += v.z; s.w += v.w;
            if (j >= POOLW-1)
                st4h(vs + (y*PT + (j - POOLW + 1))*VSTRIDE + d4*4, s);
        }
    }
    __syncthreads();

    // ---- 3b: vertical 7-window + store ----
    const float inv = 1.f / 49.f;
    float* outn = out + (size_t)n * (DD*OUTS*OUTS);
    for (int w = tid; w < 8*TT; w += THREADS) {
        int d4 = w / TT;
        int jo = w - d4*TT;
        float4 s = make_float4(0.f, 0.f, 0.f, 0.f);
        float4 ring[POOLW];
        #pragma unroll
        for (int y = 0; y < PT; ++y) {
            float4 v = ld4h(vs + (y*PT + jo)*VSTRIDE + d4*4);
            if (y >= POOLW) {
                float4 o = ring[y % POOLW];
                s.x -= o.x; s.y -= o.y; s.z -= o.z; s.w -= o.w;
            }
            ring[y % POOLW] = v;
            s.x += v.x; s.y += v.y; s.z += v.z; s.w += v.w;
            if (y >= POOLW-1) {
                int io = y - POOLW + 1;
                size_t base = ((size_t)(d4*4)*OUTS + (i0 + io))*OUTS + (j0 + jo);
                outn[base                      ] = s.x * inv;
                outn[base +   (size_t)OUTS*OUTS] = s.y * inv;
                outn[base + 2*(size_t)OUTS*OUTS] = s.z * inv;
                outn[base + 3*(size_t)OUTS*OUTS] = s.w * inv;
            }
        }
    }
}

// ====================== fused fallback (R3, proven) =========================
__global__ __launch_bounds__(THREADS, 5)
void fern_fused(const float* __restrict__ x,
                const float* __restrict__ thresholds,
                const float* __restrict__ table,
                const int*   __restrict__ chan_idx,
                const int*   __restrict__ offsets,
                float* __restrict__ out)
{
    extern __shared__ float smem[];
    float*  xs = smem;                           // [8][33][33] f32
    __half* vs = (__half*)(smem + CC*XSTRIDE);   // [625][36] f16

    const int tile = blockIdx.x;
    const int n    = tile / 36;
    const int t2   = tile - n*36;
    const int ti   = t2 / 6;
    const int tj   = t2 - ti*6;
    const int i0   = ti * TT;
    const int j0   = tj * TT;
    const int tid = threadIdx.x;

    const float* xn = x + (size_t)n * (CC*HH*WW);
    for (int idx = tid; idx < CC*XSTRIDE; idx += THREADS) {
        int c   = idx / XSTRIDE;
        int rem = idx - c*XSTRIDE;
        int r   = rem / XT;
        int col = rem - r*XT;
        xs[idx] = xn[(c*HH + (i0 + r))*WW + (j0 + col)];
    }
    __syncthreads();

    unsigned wreg[MM];
    float    creg[MM];
    if (tid < NPOSI) {
        const int y  = tid / PT;
        const int j  = tid - y*PT;
        fern_bits<XSTRIDE, XT>(xs, y*XT + j, thresholds, chan_idx, offsets,
                               wreg, creg);
    }
    __syncthreads();

    float* cbuf = smem;
    uint4* wbuf = (uint4*)(smem + 5000);

    if (tid < NPOSI) {
        uint4 wv;
        wv.x = wreg[0] | (wreg[1] << 16);
        wv.y = wreg[2] | (wreg[3] << 16);
        wv.z = wreg[4] | (wreg[5] << 16);
        wv.w = wreg[6] | (wreg[7] << 16);
        wbuf[tid] = wv;
        ((float4*)cbuf)[tid*2 + 0] = make_float4(creg[0], creg[1], creg[2], creg[3]);
        ((float4*)cbuf)[tid*2 + 1] = make_float4(creg[4], creg[5], creg[6], creg[7]);
    }
    __syncthreads();

    for (int item = tid; item < NPOSI*8; item += THREADS) {
        const int pos = item >> 3;
        const int d4  = item & 7;
        uint4  wv = wbuf[pos];
        float4 c0 = ((const float4*)cbuf)[pos*2 + 0];
        float4 c1 = ((const float4*)cbuf)[pos*2 + 1];
        const float* tb = table + d4*4;
        float4 acc = make_float4(0.f, 0.f, 0.f, 0.f);
        unsigned w; float cf; float4 tv;
#define FERN(mi, wexpr, cexpr)                                             \
        w = (wexpr); cf = (cexpr);                                         \
        tv = *(const float4*)(tb + ((size_t)(mi) << 17) + w*DD);           \
        acc.x += cf*tv.x; acc.y += cf*tv.y;                                \
        acc.z += cf*tv.z; acc.w += cf*tv.w;
        FERN(0, wv.x & 0xFFFFu, c0.x)
        FERN(1, wv.x >> 16,     c0.y)
        FERN(2, wv.y & 0xFFFFu, c0.z)
        FERN(3, wv.y >> 16,     c0.w)
        FERN(4, wv.z & 0xFFFFu, c1.x)
        FERN(5, wv.z >> 16,     c1.y)
        FERN(6, wv.w & 0xFFFFu, c1.z)
        FERN(7, wv.w >> 16,     c1.w)
#undef FERN
        st4h(vs + pos*VSTRIDE + d4*4, acc);
    }
    __syncthreads();

    for (int w = tid; w < PT*8; w += THREADS) {
        int y  = w / 8;
        int d4 = w - y*8;
        float4 s = make_float4(0.f, 0.f, 0.f, 0.f);
        float4 ring[POOLW];
        #pragma unroll
        for (int j = 0; j < PT; ++j) {
            float4 v = ld4h(vs + (y*PT + j)*VSTRIDE + d4*4);
            if (j >= POOLW) {
                float4 o = ring[j % POOLW];
                s.x -= o.x; s.y -= o.y; s.z -= o.z; s.w -= o.w;
            }
            ring[j % POOLW] = v;
            s.x += v.x; s.y += v.y; s.z += v.z; s.w += v.w;
            if (j >= POOLW-1)
                st4h(vs + (y*PT + (j - POOLW + 1))*VSTRIDE + d4*4, s);
        }
    }
    __syncthreads();

    const float inv = 1.f / 49.f;
    float* outn = out + (size_t)n * (DD*OUTS*OUTS);
    for (int w = tid; w < 8*TT; w += THREADS) {
        int d4 = w / TT;
        int jo = w - d4*TT;
        float4 s = make_float4(0.f, 0.f, 0.f, 0.f);
        float4 ring[POOLW];
        #pragma unroll
        for (int y = 0; y < PT; ++y) {
            float4 v = ld4h(vs + (y*PT + jo)*VSTRIDE + d4*4);
            if (y >= POOLW) {
                float4 o = ring[y % POOLW];
                s.x -= o.x; s.y -= o.y; s.z -= o.z; s.w -= o.w;
            }
            ring[y % POOLW] = v;
            s.x += v.x; s.y += v.y; s.z += v.z; s.w += v.w;
            if (y >= POOLW-1) {
                int io = y - POOLW + 1;
                size_t base = ((size_t)(d4*4)*OUTS + (i0 + io))*OUTS + (j0 + jo);
                outn[base                      ] = s.x * inv;
                outn[base +   (size_t)OUTS*OUTS] = s.y * inv;
                outn[base + 2*(size_t)OUTS*OUTS] = s.z * inv;
                outn[base + 3*(size_t)OUTS*OUTS] = s.w * inv;
            }
        }
    }
}

extern "C" void kernel_launch(void* const* d_in, const int* in_sizes, int n_in,
                              void* d_out, int out_size, void* d_ws, size_t ws_size,
                              hipStream_t stream) {
    const float* x          = (const float*)d_in[0];
    const float* thresholds = (const float*)d_in[1];
    const float* table      = (const float*)d_in[2];
    const int*   chan_idx   = (const int*)d_in[3];
    const int*   offsets    = (const int*)d_in[4];
    float* out = (float*)d_out;

    if (d_ws != nullptr && ws_size >= VOTE_BYTES + TAB16_BYTES) {
        __half* votes = (__half*)d_ws;
        __half* t16   = (__half*)((char*)d_ws + VOTE_BYTES);
        table_to_f16<<<dim3(TAB_ELEMS/(256*8)), dim3(256), 0, stream>>>(
            table, t16);
        fern_gather<<<dim3(NN*16), dim3(K1T), 0, stream>>>(
            x, thresholds, t16, chan_idx, offsets, votes);
        fern_pool<<<dim3(NN*36), dim3(THREADS), 0, stream>>>(votes, out);
    } else {
        // fallback: proven R3 fused kernel
        hipFuncSetAttribute((const void*)fern_fused,
                            hipFuncAttributeMaxDynamicSharedMemorySize, LDS_BYTES);
        fern_fused<<<dim3(NN*36), dim3(THREADS), LDS_BYTES, stream>>>(
            x, thresholds, table, chan_idx, offsets, out);
    }
}

// Round 6
// 344.606 us; speedup vs baseline: 1.0142x; 1.0142x over previous
//
#include <hip/hip_runtime.h>
#include <hip/hip_fp16.h>

// Fern patch-descriptor pipeline.
//   x:(64,8,128,128) f32, thresholds:(8,12) f32, table:(8,4096,32) f32,
//   chan_idx:(8,12,2) i32, offsets:(8,12,2,2) i32
//   out:(64, 32*114*114) f32
//
// R8: kill the scratch spill exposed in R7 (VGPR=32, WRITE_SIZE 450MB).
//   - fern_gather pinned to waves_per_eu(8,8): min=8 caps VGPR at 64
//     (2 blocks x 16 waves/CU); max=8 stops the allocator from chasing the
//     3-block/12-wave tier that forced a 32-reg allocation + spill in R7.
//   - gather loads batched 4-at-a-time (two half-passes reusing the same
//     4 float4 temps): live set ~48 regs < 64, 4-deep MLP per wave.
// Geometry unchanged from R7: 32x32 position tiles (40x40 halo, 51.2KB
// LDS), grid 64*16 = 1024 blocks, zero tail; seam double-writes benign.
// table f32->f16 pre-pass and fern_pool unchanged.

#define NN 64
#define CC 8
#define HH 128
#define WW 128
#define MM 8
#define KK 12
#define DD 32
#define OUTS 114
#define TT 19          // output tile edge (114 = 6*19 exact)
#define PT 25          // position tile edge = TT + POOL - 1
#define XT 33          // fused-kernel x tile edge = PT + L - 1
#define XSTRIDE (XT*XT)   // 1089
#define VSTRIDE 36        // vote row stride in halves (72 B rows, 8B-aligned)
#define NPOSI (PT*PT)     // 625
#define THREADS 640
#define POOLW 7

// K1 geometry: 120x120 unique grid, 4x4 tiles of 32x32 (starts 0,32,64,88)
#define PTK 32
#define XTK 40            // PTK + L - 1
#define XS2 (XTK*XTK)     // 1600
#define NPOS_IMG (120*120)
#define K1T 1024

#define VOTE_BYTES ((size_t)NN * NPOS_IMG * DD * 2)   // 58,982,400 B
#define TAB_ELEMS  (MM*4096*DD)                       // 1,048,576
#define TAB16_BYTES ((size_t)TAB_ELEMS * 2)           // 2,097,152 B

#define LDS_BYTES (CC*XSTRIDE*4 + NPOSI*VSTRIDE*2)   // fused fallback: 79848

// 8-byte LDS accessors: 4 halves <-> float4
__device__ __forceinline__ float4 ld4h(const __half* p) {
    union { float2 f; __half2 h[2]; } u;
    u.f = *(const float2*)p;
    float2 a = __half22float2(u.h[0]);
    float2 b = __half22float2(u.h[1]);
    return make_float4(a.x, a.y, b.x, b.y);
}
__device__ __forceinline__ void st4h(__half* p, float4 v) {
    union { float2 f; __half2 h[2]; } u;
    u.h[0] = __floats2half2_rn(v.x, v.y);
    u.h[1] = __floats2half2_rn(v.z, v.w);
    *(float2*)p = u.f;
}

// Shared bit/conf math: identical arithmetic order everywhere.
template<int XS, int XROW>
__device__ __forceinline__ void fern_bits(const float* __restrict__ xs, int pb,
                                          const float* __restrict__ thresholds,
                                          const int*   __restrict__ chan_idx,
                                          const int*   __restrict__ offsets,
                                          unsigned wreg[MM], float creg[MM])
{
    #pragma unroll
    for (int m = 0; m < MM; ++m) {
        unsigned word = 0u;
        float P = 1.f;                    // prod(1 + exp(-10|z|))
        #pragma unroll
        for (int k = 0; k < KK; ++k) {
            const int mk = m*KK + k;
            // compile-time mk -> wave-uniform scalar loads
            int c1  = chan_idx[mk*2 + 0];
            int c2  = chan_idx[mk*2 + 1];
            int dy1 = offsets[mk*4 + 0];
            int dx1 = offsets[mk*4 + 1];
            int dy2 = offsets[mk*4 + 2];
            int dx2 = offsets[mk*4 + 3];
            float thr = thresholds[mk];
            float p1 = xs[c1*XS + dy1*XROW + dx1 + pb];
            float p2 = xs[c2*XS + dy2*XROW + dx2 + pb];
            float z  = (p1 - p2) - thr;
            if (z > 0.f) word |= (1u << k);
            float e = __expf(-10.f * fabsf(z));
            P += P * e;                   // P *= (1+e), single v_fma
        }
        wreg[m] = word;
        creg[m] = __builtin_amdgcn_rcpf(P);   // conf = 1/P
    }
}

// ===================== table f32 -> f16 conversion =========================
__global__ __launch_bounds__(256)
void table_to_f16(const float* __restrict__ t, __half* __restrict__ t16)
{
    const int i = (blockIdx.x * 256 + threadIdx.x) * 8;
    float4 a = *(const float4*)(t + i);
    float4 b = *(const float4*)(t + i + 4);
    union { float4 f; __half2 h[4]; } o;
    o.h[0] = __floats2half2_rn(a.x, a.y);
    o.h[1] = __floats2half2_rn(a.z, a.w);
    o.h[2] = __floats2half2_rn(b.x, b.y);
    o.h[3] = __floats2half2_rn(b.z, b.w);
    *(float4*)(t16 + i) = o.f;
}

// ============ K1: bits + conf + f16 table gather (unique positions) ========
// waves_per_eu(8,8): VGPR budget exactly 64 (2 blocks/CU); stops the
// allocator from targeting the 3-block tier (32-40 regs) that spilled in R7.
__global__ __launch_bounds__(K1T)
__attribute__((amdgpu_waves_per_eu(8, 8)))
void fern_gather(const float* __restrict__ x,
                 const float* __restrict__ thresholds,
                 const __half* __restrict__ table16,
                 const int*   __restrict__ chan_idx,
                 const int*   __restrict__ offsets,
                 __half* __restrict__ votes)
{
    __shared__ float4 xs4[CC*XS2/4];     // 51200 B
    float* xs = (float*)xs4;

    const int tile = blockIdx.x;             // 64 images x 16 tiles
    const int n    = tile >> 4;
    const int t2   = tile & 15;
    const int ti   = t2 >> 2;
    const int tj   = t2 & 3;
    const int pi0  = ti < 3 ? ti*PTK : 88;   // starts 0,32,64,88
    const int pj0  = tj < 3 ? tj*PTK : 88;

    const int tid = threadIdx.x;

    // stage 8x40x40 f32 tile as float4 (all starts %4==0 -> aligned)
    const float* xn = x + (size_t)n * (CC*HH*WW);
    for (int idx = tid; idx < CC*XS2/4; idx += K1T) {
        int c   = idx / 400;                 // 400 float4 / channel
        int rem = idx - c*400;
        int r   = rem / 10;                  // 10 float4 / row
        int c4  = rem - r*10;
        xs4[idx] = *(const float4*)(xn + (c*HH + pi0 + r)*WW + pj0 + c4*4);
    }
    __syncthreads();

    const int ty = tid >> 5;                 // 0..31
    const int tx = tid & 31;

    unsigned wreg[MM];
    float    creg[MM];
    fern_bits<XS2, XTK>(xs, ty*XTK + tx, thresholds, chan_idx, offsets,
                        wreg, creg);
    __syncthreads();   // all xs reads complete -> xs region reusable

    // Overlay on dead xs: c0buf f4[1024] @0 (16KB), c1buf f4[1024] @16KB,
    // wbuf u4[1024] @32KB. Total 48KB <= 51.2KB.
    float4* c0buf = (float4*)xs;
    float4* c1buf = (float4*)(xs + 4096);
    uint4*  wbuf  = (uint4*)(xs + 8192);

    {
        uint4 wv;
        wv.x = wreg[0] | (wreg[1] << 16);
        wv.y = wreg[2] | (wreg[3] << 16);
        wv.z = wreg[4] | (wreg[5] << 16);
        wv.w = wreg[6] | (wreg[7] << 16);
        wbuf[tid]  = wv;
        c0buf[tid] = make_float4(creg[0], creg[1], creg[2], creg[3]);
        c1buf[tid] = make_float4(creg[4], creg[5], creg[6], creg[7]);
    }
    __syncthreads();

    // Quad-cooperative gather: item = (pos,q); 4 lanes share pos, each lane
    // reads 16B (8 halves) of the 64B f16 table row. Loads batched
    // 4-at-a-time (two half-passes reusing t0..t3): 4-deep MLP without
    // exceeding the 64-VGPR budget.
    #pragma unroll
    for (int it = 0; it < 4; ++it) {
        const int item = tid + it*K1T;
        const int pos  = item >> 2;
        const int q    = item & 3;
        uint4  wv = wbuf[pos];               // broadcast within quad
        float4 c0 = c0buf[pos];
        float4 c1 = c1buf[pos];
        const __half* tb = table16 + q*8;
        union U { float4 f; __half2 h[4]; };
        U t0, t1, t2, t3;
        float acc[8];
        #pragma unroll
        for (int j = 0; j < 8; ++j) acc[j] = 0.f;
#define ACC(T, cexpr) {                                                    \
        float cf = (cexpr);                                                \
        float2 v0 = __half22float2(T.h[0]);                                \
        float2 v1 = __half22float2(T.h[1]);                                \
        float2 v2 = __half22float2(T.h[2]);                                \
        float2 v3 = __half22float2(T.h[3]);                                \
        acc[0] += cf*v0.x; acc[1] += cf*v0.y;                              \
        acc[2] += cf*v1.x; acc[3] += cf*v1.y;                              \
        acc[4] += cf*v2.x; acc[5] += cf*v2.y;                              \
        acc[6] += cf*v3.x; acc[7] += cf*v3.y; }
        // batch 1: ferns 0..3
        t0.f = *(const float4*)(tb + ((0u<<12) + (wv.x & 0xFFFFu))*DD);
        t1.f = *(const float4*)(tb + ((1u<<12) + (wv.x >> 16    ))*DD);
        t2.f = *(const float4*)(tb + ((2u<<12) + (wv.y & 0xFFFFu))*DD);
        t3.f = *(const float4*)(tb + ((3u<<12) + (wv.y >> 16    ))*DD);
        ACC(t0, c0.x)
        ACC(t1, c0.y)
        ACC(t2, c0.z)
        ACC(t3, c0.w)
        // batch 2: ferns 4..7 (reuse t0..t3)
        t0.f = *(const float4*)(tb + ((4u<<12) + (wv.z & 0xFFFFu))*DD);
        t1.f = *(const float4*)(tb + ((5u<<12) + (wv.z >> 16    ))*DD);
        t2.f = *(const float4*)(tb + ((6u<<12) + (wv.w & 0xFFFFu))*DD);
        t3.f = *(const float4*)(tb + ((7u<<12) + (wv.w >> 16    ))*DD);
        ACC(t0, c1.x)
        ACC(t1, c1.y)
        ACC(t2, c1.z)
        ACC(t3, c1.w)
#undef ACC
        // votes[gp][q*8 .. +7] as f16: 16B/lane, quad covers the 64B row,
        // consecutive pos -> contiguous per wave. Seam double-writes carry
        // identical bytes (same inputs) -> benign.
        const int py = pos >> 5;
        const int px = pos & 31;
        const int gp = n*NPOS_IMG + (pi0 + py)*120 + (pj0 + px);
        union { float4 f; __half2 h[4]; } o;
        o.h[0] = __floats2half2_rn(acc[0], acc[1]);
        o.h[1] = __floats2half2_rn(acc[2], acc[3]);
        o.h[2] = __floats2half2_rn(acc[4], acc[5]);
        o.h[3] = __floats2half2_rn(acc[6], acc[7]);
        *(float4*)(votes + (size_t)gp*DD + q*8) = o.f;
    }
}

// ====================== K2: pooling only ===================================
__global__ __launch_bounds__(THREADS, 8)
void fern_pool(const __half* __restrict__ votes,
               float* __restrict__ out)
{
    __shared__ float2 vsraw[NPOSI*VSTRIDE/4];   // 45000 B
    __half* vs = (__half*)vsraw;

    const int tile = blockIdx.x;         // 0..2303
    const int n    = tile / 36;
    const int t2   = tile - n*36;
    const int ti   = t2 / 6;
    const int tj   = t2 - ti*6;
    const int i0   = ti * TT;            // 0..95
    const int j0   = tj * TT;

    const int tid = threadIdx.x;

    // ---- stage 25x25x32 f16 votes tile; item = (pos, oct): 8B per lane ----
    const int pbase = n*NPOS_IMG + i0*120 + j0;
    for (int idx = tid; idx < NPOSI*8; idx += THREADS) {
        const int pos = idx >> 3;
        const int oct = idx & 7;
        const int y   = pos / PT;
        const int j   = pos - y*PT;
        const __half* src = votes + (size_t)(pbase + y*120 + j)*DD + oct*4;
        *(float2*)(vs + pos*VSTRIDE + oct*4) = *(const float2*)src;
    }
    __syncthreads();

    // ---- 3a: horizontal 7-window running sums (in-place) ----
    for (int w = tid; w < PT*8; w += THREADS) {
        int y  = w / 8;
        int d4 = w - y*8;
        float4 s = make_float4(0.f, 0.f, 0.f, 0.f);
        float4 ring[POOLW];
        #pragma unroll
        for (int j = 0; j < PT; ++j) {
            float4 v = ld4h(vs + (y*PT + j)*VSTRIDE + d4*4);
            if (j >= POOLW) {
                float4 o = ring[j % POOLW];
                s.x -= o.x; s.y -= o.y; s.z -= o.z; s.w -= o.w;
            }
            ring[j % POOLW] = v;
            s.x += v.x; s.y += v.y; s.z += v.z; s.w += v.w;
            if (j >= POOLW-1)
                st4h(vs + (y*PT + (j - POOLW + 1))*VSTRIDE + d4*4, s);
        }
    }
    __syncthreads();

    // ---- 3b: vertical 7-window + store ----
    const float inv = 1.f / 49.f;
    float* outn = out + (size_t)n * (DD*OUTS*OUTS);
    for (int w = tid; w < 8*TT; w += THREADS) {
        int d4 = w / TT;
        int jo = w - d4*TT;
        float4 s = make_float4(0.f, 0.f, 0.f, 0.f);
        float4 ring[POOLW];
        #pragma unroll
        for (int y = 0; y < PT; ++y) {
            float4 v = ld4h(vs + (y*PT + jo)*VSTRIDE + d4*4);
            if (y >= POOLW) {
                float4 o = ring[y % POOLW];
                s.x -= o.x; s.y -= o.y; s.z -= o.z; s.w -= o.w;
            }
            ring[y % POOLW] = v;
            s.x += v.x; s.y += v.y; s.z += v.z; s.w += v.w;
            if (y >= POOLW-1) {
                int io = y - POOLW + 1;
                size_t base = ((size_t)(d4*4)*OUTS + (i0 + io))*OUTS + (j0 + jo);
                outn[base                      ] = s.x * inv;
                outn[base +   (size_t)OUTS*OUTS] = s.y * inv;
                outn[base + 2*(size_t)OUTS*OUTS] = s.z * inv;
                outn[base + 3*(size_t)OUTS*OUTS] = s.w * inv;
            }
        }
    }
}

// ====================== fused fallback (R3, proven) =========================
__global__ __launch_bounds__(THREADS, 5)
void fern_fused(const float* __restrict__ x,
                const float* __restrict__ thresholds,
                const float* __restrict__ table,
                const int*   __restrict__ chan_idx,
                const int*   __restrict__ offsets,
                float* __restrict__ out)
{
    extern __shared__ float smem[];
    float*  xs = smem;                           // [8][33][33] f32
    __half* vs = (__half*)(smem + CC*XSTRIDE);   // [625][36] f16

    const int tile = blockIdx.x;
    const int n    = tile / 36;
    const int t2   = tile - n*36;
    const int ti   = t2 / 6;
    const int tj   = t2 - ti*6;
    const int i0   = ti * TT;
    const int j0   = tj * TT;
    const int tid = threadIdx.x;

    const float* xn = x + (size_t)n * (CC*HH*WW);
    for (int idx = tid; idx < CC*XSTRIDE; idx += THREADS) {
        int c   = idx / XSTRIDE;
        int rem = idx - c*XSTRIDE;
        int r   = rem / XT;
        int col = rem - r*XT;
        xs[idx] = xn[(c*HH + (i0 + r))*WW + (j0 + col)];
    }
    __syncthreads();

    unsigned wreg[MM];
    float    creg[MM];
    if (tid < NPOSI) {
        const int y  = tid / PT;
        const int j  = tid - y*PT;
        fern_bits<XSTRIDE, XT>(xs, y*XT + j, thresholds, chan_idx, offsets,
                               wreg, creg);
    }
    __syncthreads();

    float* cbuf = smem;
    uint4* wbuf = (uint4*)(smem + 5000);

    if (tid < NPOSI) {
        uint4 wv;
        wv.x = wreg[0] | (wreg[1] << 16);
        wv.y = wreg[2] | (wreg[3] << 16);
        wv.z = wreg[4] | (wreg[5] << 16);
        wv.w = wreg[6] | (wreg[7] << 16);
        wbuf[tid] = wv;
        ((float4*)cbuf)[tid*2 + 0] = make_float4(creg[0], creg[1], creg[2], creg[3]);
        ((float4*)cbuf)[tid*2 + 1] = make_float4(creg[4], creg[5], creg[6], creg[7]);
    }
    __syncthreads();

    for (int item = tid; item < NPOSI*8; item += THREADS) {
        const int pos = item >> 3;
        const int d4  = item & 7;
        uint4  wv = wbuf[pos];
        float4 c0 = ((const float4*)cbuf)[pos*2 + 0];
        float4 c1 = ((const float4*)cbuf)[pos*2 + 1];
        const float* tb = table + d4*4;
        float4 acc = make_float4(0.f, 0.f, 0.f, 0.f);
        unsigned w; float cf; float4 tv;
#define FERN(mi, wexpr, cexpr)                                             \
        w = (wexpr); cf = (cexpr);                                         \
        tv = *(const float4*)(tb + ((size_t)(mi) << 17) + w*DD);           \
        acc.x += cf*tv.x; acc.y += cf*tv.y;                                \
        acc.z += cf*tv.z; acc.w += cf*tv.w;
        FERN(0, wv.x & 0xFFFFu, c0.x)
        FERN(1, wv.x >> 16,     c0.y)
        FERN(2, wv.y & 0xFFFFu, c0.z)
        FERN(3, wv.y >> 16,     c0.w)
        FERN(4, wv.z & 0xFFFFu, c1.x)
        FERN(5, wv.z >> 16,     c1.y)
        FERN(6, wv.w & 0xFFFFu, c1.z)
        FERN(7, wv.w >> 16,     c1.w)
#undef FERN
        st4h(vs + pos*VSTRIDE + d4*4, acc);
    }
    __syncthreads();

    for (int w = tid; w < PT*8; w += THREADS) {
        int y  = w / 8;
        int d4 = w - y*8;
        float4 s = make_float4(0.f, 0.f, 0.f, 0.f);
        float4 ring[POOLW];
        #pragma unroll
        for (int j = 0; j < PT; ++j) {
            float4 v = ld4h(vs + (y*PT + j)*VSTRIDE + d4*4);
            if (j >= POOLW) {
                float4 o = ring[j % POOLW];
                s.x -= o.x; s.y -= o.y; s.z -= o.z; s.w -= o.w;
            }
            ring[j % POOLW] = v;
            s.x += v.x; s.y += v.y; s.z += v.z; s.w += v.w;
            if (j >= POOLW-1)
                st4h(vs + (y*PT + (j - POOLW + 1))*VSTRIDE + d4*4, s);
        }
    }
    __syncthreads();

    const float inv = 1.f / 49.f;
    float* outn = out + (size_t)n * (DD*OUTS*OUTS);
    for (int w = tid; w < 8*TT; w += THREADS) {
        int d4 = w / TT;
        int jo = w - d4*TT;
        float4 s = make_float4(0.f, 0.f, 0.f, 0.f);
        float4 ring[POOLW];
        #pragma unroll
        for (int y = 0; y < PT; ++y) {
            float4 v = ld4h(vs + (y*PT + jo)*VSTRIDE + d4*4);
            if (y >= POOLW) {
                float4 o = ring[y % POOLW];
                s.x -= o.x; s.y -= o.y; s.z -= o.z; s.w -= o.w;
            }
            ring[y % POOLW] = v;
            s.x += v.x; s.y += v.y; s.z += v.z; s.w += v.w;
            if (y >= POOLW-1) {
                int io = y - POOLW + 1;
                size_t base = ((size_t)(d4*4)*OUTS + (i0 + io))*OUTS + (j0 + jo);
                outn[base                      ] = s.x * inv;
                outn[base +   (size_t)OUTS*OUTS] = s.y * inv;
                outn[base + 2*(size_t)OUTS*OUTS] = s.z * inv;
                outn[base + 3*(size_t)OUTS*OUTS] = s.w * inv;
            }
        }
    }
}

extern "C" void kernel_launch(void* const* d_in, const int* in_sizes, int n_in,
                              void* d_out, int out_size, void* d_ws, size_t ws_size,
                              hipStream_t stream) {
    const float* x          = (const float*)d_in[0];
    const float* thresholds = (const float*)d_in[1];
    const float* table      = (const float*)d_in[2];
    const int*   chan_idx   = (const int*)d_in[3];
    const int*   offsets    = (const int*)d_in[4];
    float* out = (float*)d_out;

    if (d_ws != nullptr && ws_size >= VOTE_BYTES + TAB16_BYTES) {
        __half* votes = (__half*)d_ws;
        __half* t16   = (__half*)((char*)d_ws + VOTE_BYTES);
        table_to_f16<<<dim3(TAB_ELEMS/(256*8)), dim3(256), 0, stream>>>(
            table, t16);
        fern_gather<<<dim3(NN*16), dim3(K1T), 0, stream>>>(
            x, thresholds, t16, chan_idx, offsets, votes);
        fern_pool<<<dim3(NN*36), dim3(THREADS), 0, stream>>>(votes, out);
    } else {
        // fallback: proven R3 fused kernel
        hipFuncSetAttribute((const void*)fern_fused,
                            hipFuncAttributeMaxDynamicSharedMemorySize, LDS_BYTES);
        fern_fused<<<dim3(NN*36), dim3(THREADS), LDS_BYTES, stream>>>(
            x, thresholds, table, chan_idx, offsets, out);
    }
}

// Round 7
// 319.573 us; speedup vs baseline: 1.0937x; 1.0783x over previous
//
#include <hip/hip_runtime.h>
#include <hip/hip_fp16.h>

// Fern patch-descriptor pipeline.
//   x:(64,8,128,128) f32, thresholds:(8,12) f32, table:(8,4096,32) f32,
//   chan_idx:(8,12,2) i32, offsets:(8,12,2,2) i32
//   out:(64, 32*114*114) f32
//
// R9: revert fern_gather to the EXACT R5 structure -- the only gather body
// that ever compiled spill-free (VGPR 56, WRITE_SIZE == votes exactly) --
// with ONE delta: f16 table + octet-cooperative 8B loads.
//   - 8 lanes share one 64B f16 table row (= ONE cache line), each lane
//     loads float2 (4 halves) -> temp is 2 regs vs R5's 4: live set
//     strictly smaller than the proven-clean R5.
//   - R6/R7/R8's acc[8]/multi-union/1024-thread restructures all produced
//     VGPR<=36 + 200-450MB scratch traffic regardless of launch bounds;
//     abandoned wholesale.
// Geometry = R5: 24x24 unique-position tiles, 32x32 halo (32KB LDS),
// 576 thr, grid 64*25. table f32->f16 pre-pass + fern_pool unchanged.

#define NN 64
#define CC 8
#define HH 128
#define WW 128
#define MM 8
#define KK 12
#define DD 32
#define OUTS 114
#define TT 19          // output tile edge (114 = 6*19 exact)
#define PT 25          // position tile edge = TT + POOL - 1
#define XT 33          // fused-kernel x tile edge = PT + L - 1
#define XSTRIDE (XT*XT)   // 1089
#define VSTRIDE 36        // vote row stride in halves (72 B rows, 8B-aligned)
#define NPOSI (PT*PT)     // 625
#define THREADS 640
#define POOLW 7

// K1 geometry: unique position grid 120x120 = 5x5 tiles of 24x24
#define PTK 24
#define XTK 32            // PTK + L - 1
#define XS2 (XTK*XTK)     // 1024
#define NPOS_IMG (120*120)
#define K1_THREADS (PTK*PTK)   // 576

#define VOTE_BYTES ((size_t)NN * NPOS_IMG * DD * 2)   // 58,982,400 B
#define TAB_ELEMS  (MM*4096*DD)                       // 1,048,576
#define TAB16_BYTES ((size_t)TAB_ELEMS * 2)           // 2,097,152 B

#define LDS_BYTES (CC*XSTRIDE*4 + NPOSI*VSTRIDE*2)   // fused fallback: 79848

// 8-byte LDS accessors: 4 halves <-> float4
__device__ __forceinline__ float4 ld4h(const __half* p) {
    union { float2 f; __half2 h[2]; } u;
    u.f = *(const float2*)p;
    float2 a = __half22float2(u.h[0]);
    float2 b = __half22float2(u.h[1]);
    return make_float4(a.x, a.y, b.x, b.y);
}
__device__ __forceinline__ void st4h(__half* p, float4 v) {
    union { float2 f; __half2 h[2]; } u;
    u.h[0] = __floats2half2_rn(v.x, v.y);
    u.h[1] = __floats2half2_rn(v.z, v.w);
    *(float2*)p = u.f;
}

// Shared bit/conf math: identical arithmetic order everywhere.
template<int XS, int XROW>
__device__ __forceinline__ void fern_bits(const float* __restrict__ xs, int pb,
                                          const float* __restrict__ thresholds,
                                          const int*   __restrict__ chan_idx,
                                          const int*   __restrict__ offsets,
                                          unsigned wreg[MM], float creg[MM])
{
    #pragma unroll
    for (int m = 0; m < MM; ++m) {
        unsigned word = 0u;
        float P = 1.f;                    // prod(1 + exp(-10|z|))
        #pragma unroll
        for (int k = 0; k < KK; ++k) {
            const int mk = m*KK + k;
            // compile-time mk -> wave-uniform scalar loads
            int c1  = chan_idx[mk*2 + 0];
            int c2  = chan_idx[mk*2 + 1];
            int dy1 = offsets[mk*4 + 0];
            int dx1 = offsets[mk*4 + 1];
            int dy2 = offsets[mk*4 + 2];
            int dx2 = offsets[mk*4 + 3];
            float thr = thresholds[mk];
            float p1 = xs[c1*XS + dy1*XROW + dx1 + pb];
            float p2 = xs[c2*XS + dy2*XROW + dx2 + pb];
            float z  = (p1 - p2) - thr;
            if (z > 0.f) word |= (1u << k);
            float e = __expf(-10.f * fabsf(z));
            P += P * e;                   // P *= (1+e), single v_fma
        }
        wreg[m] = word;
        creg[m] = __builtin_amdgcn_rcpf(P);   // conf = 1/P
    }
}

// ===================== table f32 -> f16 conversion =========================
__global__ __launch_bounds__(256)
void table_to_f16(const float* __restrict__ t, __half* __restrict__ t16)
{
    const int i = (blockIdx.x * 256 + threadIdx.x) * 8;
    float4 a = *(const float4*)(t + i);
    float4 b = *(const float4*)(t + i + 4);
    union { float4 f; __half2 h[4]; } o;
    o.h[0] = __floats2half2_rn(a.x, a.y);
    o.h[1] = __floats2half2_rn(a.z, a.w);
    o.h[2] = __floats2half2_rn(b.x, b.y);
    o.h[3] = __floats2half2_rn(b.z, b.w);
    *(float4*)(t16 + i) = o.f;
}

// ============ K1: bits + conf + f16 table gather (unique positions) ========
// EXACT R5 skeleton (proven no-spill at VGPR=56); only the table dtype and
// per-lane load width changed (16B f32 -> 8B f16).
__global__ __launch_bounds__(K1_THREADS, 8)
void fern_gather(const float* __restrict__ x,
                 const float* __restrict__ thresholds,
                 const __half* __restrict__ table16,
                 const int*   __restrict__ chan_idx,
                 const int*   __restrict__ offsets,
                 __half* __restrict__ votes)
{
    __shared__ float4 xs4[CC*XS2/4];     // 32768 B
    float* xs = (float*)xs4;

    const int tile = blockIdx.x;             // 64 images x 25 tiles
    const int n    = tile / 25;
    const int t2   = tile - n*25;
    const int pi0  = (t2 / 5) * PTK;         // 0..96
    const int pj0  = (t2 % 5) * PTK;

    const int tid = threadIdx.x;

    // stage 8x32x32 f32 tile as float4 (rows 128B, fully coalesced/aligned)
    const float* xn = x + (size_t)n * (CC*HH*WW);
    for (int idx = tid; idx < CC*XS2/4; idx += K1_THREADS) {
        int c   = idx >> 8;                  // 256 float4 / channel
        int rem = idx & 255;
        int r   = rem >> 3;                  // 8 float4 / row
        int c4  = rem & 7;
        xs4[idx] = *(const float4*)(xn + (c*HH + pi0 + r)*WW + pj0 + c4*4);
    }
    __syncthreads();

    const int ty = tid / PTK;                // 0..23
    const int tx = tid - ty*PTK;

    unsigned wreg[MM];
    float    creg[MM];
    fern_bits<XS2, XTK>(xs, ty*XTK + tx, thresholds, chan_idx, offsets,
                        wreg, creg);
    __syncthreads();   // all xs reads complete -> xs region reusable

    // Overlay on dead xs (R5 layout): conf float4[1152] @0 (18432 B),
    // words uint4[576] @18432 (9216 B). Total 27648 <= 32768 B.
    float4* cbuf = (float4*)xs;
    uint4*  wbuf = (uint4*)(xs + 4608);      // byte 18432, 16B-aligned

    {
        uint4 wv;
        wv.x = wreg[0] | (wreg[1] << 16);
        wv.y = wreg[2] | (wreg[3] << 16);
        wv.z = wreg[4] | (wreg[5] << 16);
        wv.w = wreg[6] | (wreg[7] << 16);
        wbuf[tid] = wv;
        cbuf[tid*2 + 0] = make_float4(creg[0], creg[1], creg[2], creg[3]);
        cbuf[tid*2 + 1] = make_float4(creg[4], creg[5], creg[6], creg[7]);
    }
    __syncthreads();

    // Octet-cooperative gather: item = (pos,oct); 8 consecutive lanes share
    // pos -> each FERN read covers one contiguous 64B f16 table row (ONE
    // cache line), 8B (4 halves) per lane. 576*8 items / 576 threads = 8 it.
    #pragma unroll
    for (int it = 0; it < 8; ++it) {
        const int item = tid + it*K1_THREADS;
        const int pos  = item >> 3;
        const int oct  = item & 7;
        uint4  wv = wbuf[pos];               // LDS broadcast within octet
        float4 c0 = cbuf[pos*2 + 0];
        float4 c1 = cbuf[pos*2 + 1];
        const __half* tb = table16 + oct*4;  // this lane's 4 halves of a row
        float4 acc = make_float4(0.f, 0.f, 0.f, 0.f);
        float cf;
        union { float2 f; __half2 h[2]; } u;
#define FERN16(mi, wexpr, cexpr)                                           \
        cf = (cexpr);                                                      \
        u.f = *(const float2*)(tb + (((unsigned)(mi) << 12) + (wexpr))*DD);\
        {   float2 v0 = __half22float2(u.h[0]);                            \
            float2 v1 = __half22float2(u.h[1]);                            \
            acc.x += cf*v0.x; acc.y += cf*v0.y;                            \
            acc.z += cf*v1.x; acc.w += cf*v1.y; }
        FERN16(0, wv.x & 0xFFFFu, c0.x)
        FERN16(1, wv.x >> 16,     c0.y)
        FERN16(2, wv.y & 0xFFFFu, c0.z)
        FERN16(3, wv.y >> 16,     c0.w)
        FERN16(4, wv.z & 0xFFFFu, c1.x)
        FERN16(5, wv.z >> 16,     c1.y)
        FERN16(6, wv.w & 0xFFFFu, c1.z)
        FERN16(7, wv.w >> 16,     c1.w)
#undef FERN16
        // votes[gp][oct*4 .. +3] as f16: 8B/lane, octet covers the 64B row,
        // consecutive pos -> 512B contiguous per wave
        const int py = pos / PTK;
        const int px = pos - py*PTK;
        const int gp = n*NPOS_IMG + (pi0 + py)*120 + (pj0 + px);
        union { float2 f; __half2 h[2]; } o;
        o.h[0] = __floats2half2_rn(acc.x, acc.y);
        o.h[1] = __floats2half2_rn(acc.z, acc.w);
        *(float2*)(votes + (size_t)gp*DD + oct*4) = o.f;
    }
}

// ====================== K2: pooling only ===================================
__global__ __launch_bounds__(THREADS, 8)
void fern_pool(const __half* __restrict__ votes,
               float* __restrict__ out)
{
    __shared__ float2 vsraw[NPOSI*VSTRIDE/4];   // 45000 B
    __half* vs = (__half*)vsraw;

    const int tile = blockIdx.x;         // 0..2303
    const int n    = tile / 36;
    const int t2   = tile - n*36;
    const int ti   = t2 / 6;
    const int tj   = t2 - ti*6;
    const int i0   = ti * TT;            // 0..95
    const int j0   = tj * TT;

    const int tid = threadIdx.x;

    // ---- stage 25x25x32 f16 votes tile; item = (pos, oct): 8B per lane ----
    const int pbase = n*NPOS_IMG + i0*120 + j0;
    for (int idx = tid; idx < NPOSI*8; idx += THREADS) {
        const int pos = idx >> 3;
        const int oct = idx & 7;
        const int y   = pos / PT;
        const int j   = pos - y*PT;
        const __half* src = votes + (size_t)(pbase + y*120 + j)*DD + oct*4;
        *(float2*)(vs + pos*VSTRIDE + oct*4) = *(const float2*)src;
    }
    __syncthreads();

    // ---- 3a: horizontal 7-window running sums (in-place) ----
    for (int w = tid; w < PT*8; w += THREADS) {
        int y  = w / 8;
        int d4 = w - y*8;
        float4 s = make_float4(0.f, 0.f, 0.f, 0.f);
        float4 ring[POOLW];
        #pragma unroll
        for (int j = 0; j < PT; ++j) {
            float4 v = ld4h(vs + (y*PT + j)*VSTRIDE + d4*4);
            if (j >= POOLW) {
                float4 o = ring[j % POOLW];
                s.x -= o.x; s.y -= o.y; s.z -= o.z; s.w -= o.w;
            }
            ring[j % POOLW] = v;
            s.x += v.x; s.y += v.y; s.z += v.z; s.w += v.w;
            if (j >= POOLW-1)
                st4h(vs + (y*PT + (j - POOLW + 1))*VSTRIDE + d4*4, s);
        }
    }
    __syncthreads();

    // ---- 3b: vertical 7-window + store ----
    const float inv = 1.f / 49.f;
    float* outn = out + (size_t)n * (DD*OUTS*OUTS);
    for (int w = tid; w < 8*TT; w += THREADS) {
        int d4 = w / TT;
        int jo = w - d4*TT;
        float4 s = make_float4(0.f, 0.f, 0.f, 0.f);
        float4 ring[POOLW];
        #pragma unroll
        for (int y = 0; y < PT; ++y) {
            float4 v = ld4h(vs + (y*PT + jo)*VSTRIDE + d4*4);
            if (y >= POOLW) {
                float4 o = ring[y % POOLW];
                s.x -= o.x; s.y -= o.y; s.z -= o.z; s.w -= o.w;
            }
            ring[y % POOLW] = v;
            s.x += v.x; s.y += v.y; s.z += v.z; s.w += v.w;
            if (y >= POOLW-1) {
                int io = y - POOLW + 1;
                size_t base = ((size_t)(d4*4)*OUTS + (i0 + io))*OUTS + (j0 + jo);
                outn[base                      ] = s.x * inv;
                outn[base +   (size_t)OUTS*OUTS] = s.y * inv;
                outn[base + 2*(size_t)OUTS*OUTS] = s.z * inv;
                outn[base + 3*(size_t)OUTS*OUTS] = s.w * inv;
            }
        }
    }
}

// ====================== fused fallback (R3, proven) =========================
__global__ __launch_bounds__(THREADS, 5)
void fern_fused(const float* __restrict__ x,
                const float* __restrict__ thresholds,
                const float* __restrict__ table,
                const int*   __restrict__ chan_idx,
                const int*   __restrict__ offsets,
                float* __restrict__ out)
{
    extern __shared__ float smem[];
    float*  xs = smem;                           // [8][33][33] f32
    __half* vs = (__half*)(smem + CC*XSTRIDE);   // [625][36] f16

    const int tile = blockIdx.x;
    const int n    = tile / 36;
    const int t2   = tile - n*36;
    const int ti   = t2 / 6;
    const int tj   = t2 - ti*6;
    const int i0   = ti * TT;
    const int j0   = tj * TT;
    const int tid = threadIdx.x;

    const float* xn = x + (size_t)n * (CC*HH*WW);
    for (int idx = tid; idx < CC*XSTRIDE; idx += THREADS) {
        int c   = idx / XSTRIDE;
        int rem = idx - c*XSTRIDE;
        int r   = rem / XT;
        int col = rem - r*XT;
        xs[idx] = xn[(c*HH + (i0 + r))*WW + (j0 + col)];
    }
    __syncthreads();

    unsigned wreg[MM];
    float    creg[MM];
    if (tid < NPOSI) {
        const int y  = tid / PT;
        const int j  = tid - y*PT;
        fern_bits<XSTRIDE, XT>(xs, y*XT + j, thresholds, chan_idx, offsets,
                               wreg, creg);
    }
    __syncthreads();

    float* cbuf = smem;
    uint4* wbuf = (uint4*)(smem + 5000);

    if (tid < NPOSI) {
        uint4 wv;
        wv.x = wreg[0] | (wreg[1] << 16);
        wv.y = wreg[2] | (wreg[3] << 16);
        wv.z = wreg[4] | (wreg[5] << 16);
        wv.w = wreg[6] | (wreg[7] << 16);
        wbuf[tid] = wv;
        ((float4*)cbuf)[tid*2 + 0] = make_float4(creg[0], creg[1], creg[2], creg[3]);
        ((float4*)cbuf)[tid*2 + 1] = make_float4(creg[4], creg[5], creg[6], creg[7]);
    }
    __syncthreads();

    for (int item = tid; item < NPOSI*8; item += THREADS) {
        const int pos = item >> 3;
        const int d4  = item & 7;
        uint4  wv = wbuf[pos];
        float4 c0 = ((const float4*)cbuf)[pos*2 + 0];
        float4 c1 = ((const float4*)cbuf)[pos*2 + 1];
        const float* tb = table + d4*4;
        float4 acc = make_float4(0.f, 0.f, 0.f, 0.f);
        unsigned w; float cf; float4 tv;
#define FERN(mi, wexpr, cexpr)                                             \
        w = (wexpr); cf = (cexpr);                                         \
        tv = *(const float4*)(tb + ((size_t)(mi) << 17) + w*DD);           \
        acc.x += cf*tv.x; acc.y += cf*tv.y;                                \
        acc.z += cf*tv.z; acc.w += cf*tv.w;
        FERN(0, wv.x & 0xFFFFu, c0.x)
        FERN(1, wv.x >> 16,     c0.y)
        FERN(2, wv.y & 0xFFFFu, c0.z)
        FERN(3, wv.y >> 16,     c0.w)
        FERN(4, wv.z & 0xFFFFu, c1.x)
        FERN(5, wv.z >> 16,     c1.y)
        FERN(6, wv.w & 0xFFFFu, c1.z)
        FERN(7, wv.w >> 16,     c1.w)
#undef FERN
        st4h(vs + pos*VSTRIDE + d4*4, acc);
    }
    __syncthreads();

    for (int w = tid; w < PT*8; w += THREADS) {
        int y  = w / 8;
        int d4 = w - y*8;
        float4 s = make_float4(0.f, 0.f, 0.f, 0.f);
        float4 ring[POOLW];
        #pragma unroll
        for (int j = 0; j < PT; ++j) {
            float4 v = ld4h(vs + (y*PT + j)*VSTRIDE + d4*4);
            if (j >= POOLW) {
                float4 o = ring[j % POOLW];
                s.x -= o.x; s.y -= o.y; s.z -= o.z; s.w -= o.w;
            }
            ring[j % POOLW] = v;
            s.x += v.x; s.y += v.y; s.z += v.z; s.w += v.w;
            if (j >= POOLW-1)
                st4h(vs + (y*PT + (j - POOLW + 1))*VSTRIDE + d4*4, s);
        }
    }
    __syncthreads();

    const float inv = 1.f / 49.f;
    float* outn = out + (size_t)n * (DD*OUTS*OUTS);
    for (int w = tid; w < 8*TT; w += THREADS) {
        int d4 = w / TT;
        int jo = w - d4*TT;
        float4 s = make_float4(0.f, 0.f, 0.f, 0.f);
        float4 ring[POOLW];
        #pragma unroll
        for (int y = 0; y < PT; ++y) {
            float4 v = ld4h(vs + (y*PT + jo)*VSTRIDE + d4*4);
            if (y >= POOLW) {
                float4 o = ring[y % POOLW];
                s.x -= o.x; s.y -= o.y; s.z -= o.z; s.w -= o.w;
            }
            ring[y % POOLW] = v;
            s.x += v.x; s.y += v.y; s.z += v.z; s.w += v.w;
            if (y >= POOLW-1) {
                int io = y - POOLW + 1;
                size_t base = ((size_t)(d4*4)*OUTS + (i0 + io))*OUTS + (j0 + jo);
                outn[base                      ] = s.x * inv;
                outn[base +   (size_t)OUTS*OUTS] = s.y * inv;
                outn[base + 2*(size_t)OUTS*OUTS] = s.z * inv;
                outn[base + 3*(size_t)OUTS*OUTS] = s.w * inv;
            }
        }
    }
}

extern "C" void kernel_launch(void* const* d_in, const int* in_sizes, int n_in,
                              void* d_out, int out_size, void* d_ws, size_t ws_size,
                              hipStream_t stream) {
    const float* x          = (const float*)d_in[0];
    const float* thresholds = (const float*)d_in[1];
    const float* table      = (const float*)d_in[2];
    const int*   chan_idx   = (const int*)d_in[3];
    const int*   offsets    = (const int*)d_in[4];
    float* out = (float*)d_out;

    if (d_ws != nullptr && ws_size >= VOTE_BYTES + TAB16_BYTES) {
        __half* votes = (__half*)d_ws;
        __half* t16   = (__half*)((char*)d_ws + VOTE_BYTES);
        table_to_f16<<<dim3(TAB_ELEMS/(256*8)), dim3(256), 0, stream>>>(
            table, t16);
        fern_gather<<<dim3(NN*25), dim3(K1_THREADS), 0, stream>>>(
            x, thresholds, t16, chan_idx, offsets, votes);
        fern_pool<<<dim3(NN*36), dim3(THREADS), 0, stream>>>(votes, out);
    } else {
        // fallback: proven R3 fused kernel
        hipFuncSetAttribute((const void*)fern_fused,
                            hipFuncAttributeMaxDynamicSharedMemorySize, LDS_BYTES);
        fern_fused<<<dim3(NN*36), dim3(THREADS), LDS_BYTES, stream>>>(
            x, thresholds, table, chan_idx, offsets, out);
    }
}